// Round 2
// baseline (455.261 us; speedup 1.0000x reference)
//
#include <hip/hip_runtime.h>
#include <cstdint>
#include <cstddef>

// FlowNet-C correlation, MI355X fp32 (round-1 resubmit; round-0 bench was an
// infra failure: "container failed twice", no kernel diagnostics).
// B=8 C=256 H=64 W=96, PAD=MAXD=20, K=1, S1=1, S2=2 -> 441 output channels.
// out[b, dy*21+dx, y, x] = (1/256) * sum_c in1[b,c,y,x] * in2[b,c,y+2(dy-10), x+2(dx-10)]
// (zero outside the image).

constexpr int B_ = 8, C_ = 256, H_ = 64, W_ = 96;
constexpr int D_ = 21;               // displacement grid width (per axis)
constexpr int CH = 8;                // channels staged per LDS chunk
constexpr int NROW = 7;              // dy values per block (3 groups cover 21)
constexpr int S2COLS = 144;          // padded in2 window: x' in [-20,123] -> col = x'+20

// Block = (b, y, dyg). Threads: 252 active = 7 dy * (12 x-tiles * 3 dx-tiles).
// Thread tile: 8x * 8dx accumulators; s2 window per thread = 22 contiguous floats.

__global__ __launch_bounds__(256) void corr_fp32(
    const float* __restrict__ in1,
    const float* __restrict__ in2,
    float* __restrict__ out)
{
    __shared__ alignas(16) float s1[CH][W_];            // 3 KB
    __shared__ alignas(16) float s2[CH][NROW][S2COLS];  // 31.5 KB

    const int id  = blockIdx.x;
    const int b   = id & 7;         // b fastest -> one batch per XCD (round-robin)
    const int s   = id >> 3;
    const int y   = s / 3;          // y-major -> 41-row in2 window stays in L2
    const int dyg = s - y * 3;

    const int tid = threadIdx.x;

    // ---- one-time zero fill: pad columns (cols4 0..4 and 29..35) ----
    for (int u = tid; u < CH * NROW * 12; u += 256) {
        int j = u / (NROW * 12);
        int v = u - j * (NROW * 12);
        int r = v / 12;
        int p = v - r * 12;
        int col4 = (p < 5) ? p : (p + 24);
        ((float4*)&s2[j][r][0])[col4] = float4{0.f, 0.f, 0.f, 0.f};
    }
    // ---- one-time zero fill: interiors of rows whose y2 is out of bounds ----
    for (int u = tid; u < CH * NROW * 24; u += 256) {
        int j = u / (NROW * 24);
        int v = u - j * (NROW * 24);
        int r = v / 24;
        int q = v - r * 24;
        int y2 = y + 2 * (dyg * NROW + r) - 20;
        if (y2 < 0 || y2 >= H_)
            ((float4*)&s2[j][r][0])[5 + q] = float4{0.f, 0.f, 0.f, 0.f};
    }

    // ---- precompute staging descriptors (constant across chunks except +cstride) ----
    // s1: 192 slots (j 0..7, q 0..23)
    const float* g1 = nullptr;
    float4* l1 = nullptr;
    if (tid < CH * 24) {
        int j = tid / 24, q = tid - (tid / 24) * 24;
        g1 = in1 + ((size_t)(b * C_ + j) * H_ + y) * W_ + q * 4;
        l1 = ((float4*)&s1[j][0]) + q;
    }
    // s2 interior: 1344 slots -> up to 6 per thread
    const float* g2[6];
    float4*      l2[6];
    bool         v2[6];
    #pragma unroll
    for (int it = 0; it < 6; ++it) {
        int u = tid + it * 256;
        bool ok = (u < CH * NROW * 24);
        int uc = ok ? u : 0;
        int j = uc / (NROW * 24);
        int v = uc - j * (NROW * 24);
        int r = v / 24;
        int q = v - r * 24;
        int y2 = y + 2 * (dyg * NROW + r) - 20;
        ok = ok && (y2 >= 0) && (y2 < H_);
        int y2c = ok ? y2 : 0;
        int jc  = ok ? j : 0;
        g2[it] = in2 + ((size_t)(b * C_ + jc) * H_ + y2c) * W_ + (ok ? q : 0) * 4;
        l2[it] = ((float4*)&s2[jc][ok ? r : 0][0]) + 5 + (ok ? q : 0);
        v2[it] = ok;
    }

    // ---- thread compute tile ----
    const int dyj  = tid / 36;          // 0..6 (tid<252)
    const int tile = tid - dyj * 36;
    const int tx   = tile % 12;
    const int tdx  = tile / 12;
    const int x0   = tx * 8;
    const int dx0  = tdx * 8;
    const bool active = (tid < 252);

    float acc[8][8];
    #pragma unroll
    for (int k = 0; k < 8; ++k)
        #pragma unroll
        for (int i = 0; i < 8; ++i) acc[k][i] = 0.f;

    constexpr size_t cstride = (size_t)CH * H_ * W_;   // advance 8 channels

    for (int cc = 0; cc < C_; cc += CH) {
        __syncthreads();   // staging buffer free (also covers one-time zero fills)
        if (g1) *l1 = *(const float4*)g1;
        #pragma unroll
        for (int it = 0; it < 6; ++it)
            if (v2[it]) *l2[it] = *(const float4*)g2[it];
        __syncthreads();   // staging complete

        if (active) {
            #pragma unroll
            for (int j = 0; j < CH; ++j) {
                float a[8];
                float w[22];
                *(float4*)&a[0] = *(const float4*)&s1[j][x0];
                *(float4*)&a[4] = *(const float4*)&s1[j][x0 + 4];
                const float* brow = &s2[j][dyj][x0 + 2 * dx0];
                #pragma unroll
                for (int q = 0; q < 5; ++q)
                    *(float4*)&w[4 * q] = *(const float4*)&brow[4 * q];
                *(float2*)&w[20] = *(const float2*)&brow[20];
                #pragma unroll
                for (int k = 0; k < 8; ++k)
                    #pragma unroll
                    for (int i = 0; i < 8; ++i)
                        acc[k][i] = fmaf(a[i], w[i + 2 * k], acc[k][i]);
            }
        }
        if (g1) g1 += cstride;
        #pragma unroll
        for (int it = 0; it < 6; ++it) g2[it] += cstride;
    }

    if (active) {
        const int dy = dyg * NROW + dyj;
        const float sc = 1.0f / 256.0f;
        #pragma unroll
        for (int k = 0; k < 8; ++k) {
            int dx = dx0 + k;
            if (dx < D_) {
                int d = dy * D_ + dx;
                float* po = out + ((size_t)(b * (D_ * D_) + d) * H_ + y) * W_ + x0;
                float4 v0{acc[k][0] * sc, acc[k][1] * sc, acc[k][2] * sc, acc[k][3] * sc};
                float4 v1{acc[k][4] * sc, acc[k][5] * sc, acc[k][6] * sc, acc[k][7] * sc};
                ((float4*)po)[0] = v0;
                ((float4*)po)[1] = v1;
            }
        }
    }
}

extern "C" void kernel_launch(void* const* d_in, const int* in_sizes, int n_in,
                              void* d_out, int out_size, void* d_ws, size_t ws_size,
                              hipStream_t stream) {
    const float* in1 = (const float*)d_in[0];
    const float* in2 = (const float*)d_in[1];
    float* out = (float*)d_out;
    (void)in_sizes; (void)n_in; (void)d_ws; (void)ws_size; (void)out_size;
    dim3 grid(B_ * H_ * 3);   // 1536 blocks: (b fastest, then dyg, then y)
    corr_fp32<<<grid, dim3(256), 0, stream>>>(in1, in2, out);
}

// Round 4
// 453.562 us; speedup vs baseline: 1.0037x; 1.0037x over previous
//
#include <hip/hip_runtime.h>
#include <cstdint>
#include <cstddef>

// FlowNet-C correlation, MI355X fp32 (round-3: unchanged resubmit of round-2;
// the R2 bench died with a broker-level "container failed twice" infra error,
// same as R0 which passed on plain resubmission).
// B=8 C=256 H=64 W=96, PAD=MAXD=20, K=1, S1=1, S2=2 -> 441 output channels.
// out[b, dy*21+dx, y, x] = (1/256) * sum_c in1[b,c,y,x] * in2[b,c,y+2(dy-10), x+2(dx-10)]
//
// R2 changes vs R1 (LDS-conflict + occupancy bound, VALUBusy 26%, 4.2e7 conflicts):
//  - S2COLS 144 -> 164 (== 4 mod 32): spreads per-instr float4 chunk starts over
//    all 4-aligned bank positions (worst bank load ~9 vs floor 8, was ~4-8 way).
//  - CH 8 -> 4, NROW 7 -> 3, block 256 -> 128 threads: LDS 35.3 KB -> 9.4 KB,
//    grid 1536 -> 3584 blocks => ~8 resident blocks/CU instead of ~2.

constexpr int B_ = 8, C_ = 256, H_ = 64, W_ = 96;
constexpr int D_ = 21;               // displacement grid width (per axis)
constexpr int CH = 4;                // channels staged per LDS chunk
constexpr int NROW = 3;              // dy values per block (7 groups cover 21)
constexpr int NDYG = 7;
constexpr int S2COLS = 164;          // 20 pad | 96 interior | 48 pad; ==4 mod 32
constexpr int THREADS = 128;

__global__ __launch_bounds__(THREADS, 4) void corr_fp32(
    const float* __restrict__ in1,
    const float* __restrict__ in2,
    float* __restrict__ out)
{
    __shared__ alignas(16) float s1[CH][W_];            // 1.5 KB
    __shared__ alignas(16) float s2[CH][NROW][S2COLS];  // 7.9 KB

    const int id  = blockIdx.x;
    const int b   = id & 7;         // b fastest -> XCD round-robin
    const int s   = id >> 3;
    const int y   = s / NDYG;       // y-major -> in2 41-row window L2-resident
    const int dyg = s - y * NDYG;

    const int tid = threadIdx.x;

    // ---- one-time zero fill: pad float4 cols 0..4 and 29..40 (17 per row) ----
    for (int u = tid; u < CH * NROW * 17; u += THREADS) {
        int j = u / (NROW * 17);
        int v = u - j * (NROW * 17);
        int r = v / 17;
        int p = v - r * 17;
        int col4 = (p < 5) ? p : (p + 24);
        ((float4*)&s2[j][r][0])[col4] = float4{0.f, 0.f, 0.f, 0.f};
    }
    // ---- one-time zero fill: interiors of rows whose y2 is out of bounds ----
    for (int u = tid; u < CH * NROW * 24; u += THREADS) {
        int j = u / (NROW * 24);
        int v = u - j * (NROW * 24);
        int r = v / 24;
        int q = v - r * 24;
        int y2 = y + 2 * (dyg * NROW + r) - 20;
        if (y2 < 0 || y2 >= H_)
            ((float4*)&s2[j][r][0])[5 + q] = float4{0.f, 0.f, 0.f, 0.f};
    }

    // ---- staging descriptors ----
    // s1: CH*24 = 96 float4 slots
    const float* g1 = nullptr;
    float4* l1 = nullptr;
    if (tid < CH * 24) {
        int j = tid / 24, q = tid - (tid / 24) * 24;
        g1 = in1 + ((size_t)(b * C_ + j) * H_ + y) * W_ + q * 4;
        l1 = ((float4*)&s1[j][0]) + q;
    }
    // s2 interior: CH*NROW*24 = 288 slots -> up to 3 per thread
    const float* g2[3];
    float4*      l2[3];
    bool         v2[3];
    #pragma unroll
    for (int it = 0; it < 3; ++it) {
        int u = tid + it * THREADS;
        bool ok = (u < CH * NROW * 24);
        int uc = ok ? u : 0;
        int j = uc / (NROW * 24);
        int v = uc - j * (NROW * 24);
        int r = v / 24;
        int q = v - r * 24;
        int y2 = y + 2 * (dyg * NROW + r) - 20;
        ok = ok && (y2 >= 0) && (y2 < H_);
        int y2c = ok ? y2 : 0;
        int jc  = ok ? j : 0;
        g2[it] = in2 + ((size_t)(b * C_ + jc) * H_ + y2c) * W_ + (ok ? q : 0) * 4;
        l2[it] = ((float4*)&s2[jc][ok ? r : 0][0]) + 5 + (ok ? q : 0);
        v2[it] = ok;
    }

    // ---- thread compute tile: (dyj, tdx, tx) -> 8x * 8dx accumulators ----
    const int dyj  = tid / 36;          // 0..2 (tid<108)
    const int tile = tid - dyj * 36;
    const int tx   = tile % 12;
    const int tdx  = tile / 12;
    const int x0   = tx * 8;
    const int dx0  = tdx * 8;
    const bool active = (tid < NROW * 36);

    float acc[8][8];
    #pragma unroll
    for (int k = 0; k < 8; ++k)
        #pragma unroll
        for (int i = 0; i < 8; ++i) acc[k][i] = 0.f;

    constexpr size_t cstride = (size_t)CH * H_ * W_;   // advance CH channels

    for (int cc = 0; cc < C_; cc += CH) {
        __syncthreads();   // staging buffer free (covers one-time fills at cc=0)
        if (g1) *l1 = *(const float4*)g1;
        #pragma unroll
        for (int it = 0; it < 3; ++it)
            if (v2[it]) *l2[it] = *(const float4*)g2[it];
        __syncthreads();   // staging complete

        if (active) {
            #pragma unroll
            for (int j = 0; j < CH; ++j) {
                float a[8];
                float w[24];
                *(float4*)&a[0] = *(const float4*)&s1[j][x0];
                *(float4*)&a[4] = *(const float4*)&s1[j][x0 + 4];
                const float* brow = &s2[j][dyj][x0 + 2 * dx0];
                #pragma unroll
                for (int q = 0; q < 6; ++q)
                    *(float4*)&w[4 * q] = *(const float4*)&brow[4 * q];
                #pragma unroll
                for (int k = 0; k < 8; ++k)
                    #pragma unroll
                    for (int i = 0; i < 8; ++i)
                        acc[k][i] = fmaf(a[i], w[i + 2 * k], acc[k][i]);
            }
        }
        if (g1) g1 += cstride;
        #pragma unroll
        for (int it = 0; it < 3; ++it) g2[it] += cstride;
    }

    if (active) {
        const int dy = dyg * NROW + dyj;
        const float sc = 1.0f / 256.0f;
        #pragma unroll
        for (int k = 0; k < 8; ++k) {
            int dx = dx0 + k;
            if (dx < D_) {
                int d = dy * D_ + dx;
                float* po = out + ((size_t)(b * (D_ * D_) + d) * H_ + y) * W_ + x0;
                float4 v0{acc[k][0] * sc, acc[k][1] * sc, acc[k][2] * sc, acc[k][3] * sc};
                float4 v1{acc[k][4] * sc, acc[k][5] * sc, acc[k][6] * sc, acc[k][7] * sc};
                ((float4*)po)[0] = v0;
                ((float4*)po)[1] = v1;
            }
        }
    }
}

extern "C" void kernel_launch(void* const* d_in, const int* in_sizes, int n_in,
                              void* d_out, int out_size, void* d_ws, size_t ws_size,
                              hipStream_t stream) {
    const float* in1 = (const float*)d_in[0];
    const float* in2 = (const float*)d_in[1];
    float* out = (float*)d_out;
    (void)in_sizes; (void)n_in; (void)d_ws; (void)ws_size; (void)out_size;
    dim3 grid(B_ * H_ * NDYG);   // 3584 blocks: (b fastest, then dyg, then y)
    corr_fp32<<<grid, dim3(THREADS), 0, stream>>>(in1, in2, out);
}